// Round 6
// baseline (539.095 us; speedup 1.0000x reference)
//
#include <hip/hip_runtime.h>
#include <hip/hip_fp16.h>

// Problem: B=8, N=2048, D=1024, ATT=128   (all I/O float32)
//   f = x@Wf + bf ; g = x@Wg + bg ; out = softmax(f g^T) @ x + x
// Round 6: PV on full-rate 16x16x32 (P exits QK in K=32 A-layout via a
// staging-write permutation of g rows); TM=64; l-sum reduction hoisted out
// of the loop; fgmm computes f AND g per block (x read once).

#define B_ 8
#define N_ 2048
#define D_ 1024
#define A_ 128

typedef _Float16 half8v  __attribute__((ext_vector_type(8)));
typedef _Float16 half4v  __attribute__((ext_vector_type(4)));
typedef float    floatx4 __attribute__((ext_vector_type(4)));

__device__ __forceinline__ floatx4 mfma32(half8v a, half8v b, floatx4 c) {
#if defined(__HIP_DEVICE_COMPILE__)
    return __builtin_amdgcn_mfma_f32_16x16x32_f16(a, b, c, 0, 0, 0);
#else
    return c;
#endif
}

// ---------------------------------------------------------------------------
// Kernel 0: transpose+convert x [b][n][d] fp32 -> xT [b][d][n] f16.
// ---------------------------------------------------------------------------
__global__ __launch_bounds__(256) void xpose_kernel(
    const float* __restrict__ x, _Float16* __restrict__ xT)
{
    __shared__ __align__(16) _Float16 ts[64][80];
    const int n0 = blockIdx.x * 64, d0 = blockIdx.y * 64, b = blockIdx.z;
    const int t = threadIdx.x;
#pragma unroll
    for (int s = 0; s < 4; ++s) {
        int idx = t + 256 * s;
        int nl = idx >> 4, c4 = idx & 15;
        float4 v = ((const float4*)(x + ((size_t)(b * N_ + n0 + nl)) * D_ + d0))[c4];
        ts[c4 * 4 + 0][nl] = (_Float16)v.x;
        ts[c4 * 4 + 1][nl] = (_Float16)v.y;
        ts[c4 * 4 + 2][nl] = (_Float16)v.z;
        ts[c4 * 4 + 3][nl] = (_Float16)v.w;
    }
    __syncthreads();
#pragma unroll
    for (int s = 0; s < 2; ++s) {
        int idx = t + 256 * s;
        int dl = idx >> 3, c = idx & 7;
        *(uint4*)&xT[((size_t)b * D_ + d0 + dl) * N_ + n0 + c * 8] =
            *(const uint4*)&ts[dl][c * 8];
    }
}

// ---------------------------------------------------------------------------
// Kernel 0b: W [1024][128] f32 -> whT [2][128][1024] f16 (transposed, K-major)
// ---------------------------------------------------------------------------
__global__ __launch_bounds__(256) void wprep_kernel(
    const float* __restrict__ Wf, const float* __restrict__ Wg,
    _Float16* __restrict__ whT)
{
    __shared__ __align__(16) _Float16 ts[64][72];
    const int k0 = blockIdx.x * 64, c0 = blockIdx.y * 64;
    const float* W = blockIdx.z ? Wg : Wf;
    _Float16* dst = whT + (size_t)blockIdx.z * A_ * D_;
    const int t = threadIdx.x;
#pragma unroll
    for (int s = 0; s < 4; ++s) {
        int idx = t + 256 * s;
        int kl = idx >> 4, c4 = idx & 15;
        float4 v = *(const float4*)&W[(size_t)(k0 + kl) * A_ + c0 + c4 * 4];
        ts[c4 * 4 + 0][kl] = (_Float16)v.x;
        ts[c4 * 4 + 1][kl] = (_Float16)v.y;
        ts[c4 * 4 + 2][kl] = (_Float16)v.z;
        ts[c4 * 4 + 3][kl] = (_Float16)v.w;
    }
    __syncthreads();
#pragma unroll
    for (int s = 0; s < 2; ++s) {
        int idx = t + 256 * s;
        int cl = idx >> 3, ch = idx & 7;
        *(uint4*)&dst[(size_t)(c0 + cl) * D_ + k0 + ch * 8] =
            *(const uint4*)&ts[cl][ch * 8];
    }
}

// ---------------------------------------------------------------------------
// Kernel 1: MFMA GEMM, f AND g per block (x staged once).
// Block 64 rows x 256 cols (f:0-127, g:128-255), 4 waves 2x2 (32 rows x 128
// cols each). K-tile 32 with register prefetch; LDS stride 40 halves.
// ---------------------------------------------------------------------------
__global__ __launch_bounds__(256) void fgmm_kernel(
    const float* __restrict__ x, const _Float16* __restrict__ whT,
    const float* __restrict__ bfv, const float* __restrict__ bgv,
    _Float16* __restrict__ fh, _Float16* __restrict__ gh)
{
    __shared__ __align__(16) _Float16 xs[64 * 40];
    __shared__ __align__(16) _Float16 wt[256 * 40];
    const int row0 = blockIdx.x * 64;
    const int t = threadIdx.x;
    const int w = t >> 6, lane = t & 63, quad = lane >> 4, l16 = lane & 15;
    const int wr  = (w >> 1) * 32;          // wave row base
    const int wch = (w & 1);                // 0 = f cols, 1 = g cols

    float4 xRf[2];
    uint4  wR[4];
#define FG_LOAD_TILE(K0)                                                      \
    {                                                                         \
        _Pragma("unroll")                                                     \
        for (int s = 0; s < 2; ++s) {                                         \
            int idx = t + 256 * s;                                            \
            int r = idx >> 3, k4 = idx & 7;                                   \
            xRf[s] = *(const float4*)&x[(size_t)(row0 + r) * D_ + (K0) + k4 * 4]; \
        }                                                                     \
        _Pragma("unroll")                                                     \
        for (int s = 0; s < 4; ++s) {                                         \
            int idx = t + 256 * s;                                            \
            int c = idx >> 2, k8 = idx & 3;                                   \
            wR[s] = *(const uint4*)&whT[(size_t)c * D_ + (K0) + k8 * 8];      \
        }                                                                     \
    }

    FG_LOAD_TILE(0)

    floatx4 acc[2][8];
#pragma unroll
    for (int ms = 0; ms < 2; ++ms)
#pragma unroll
        for (int nt = 0; nt < 8; ++nt)
            acc[ms][nt] = (floatx4){0.f, 0.f, 0.f, 0.f};

    for (int kt = 0; kt < 32; ++kt) {
        __syncthreads();
#pragma unroll
        for (int s = 0; s < 2; ++s) {
            int idx = t + 256 * s;
            int r = idx >> 3, k4 = idx & 7;
            half4v h = {(_Float16)xRf[s].x, (_Float16)xRf[s].y,
                        (_Float16)xRf[s].z, (_Float16)xRf[s].w};
            *(half4v*)&xs[r * 40 + k4 * 4] = h;
        }
#pragma unroll
        for (int s = 0; s < 4; ++s) {
            int idx = t + 256 * s;
            int c = idx >> 2, k8 = idx & 3;
            *(uint4*)&wt[c * 40 + k8 * 8] = wR[s];
        }
        __syncthreads();
        if (kt < 31) FG_LOAD_TILE((kt + 1) * 32)

        half8v a0 = *(const half8v*)&xs[(wr + l16) * 40 + quad * 8];
        half8v a1 = *(const half8v*)&xs[(wr + 16 + l16) * 40 + quad * 8];
#pragma unroll
        for (int nt = 0; nt < 8; ++nt) {
            half8v bfr = *(const half8v*)&wt[(wch * 128 + nt * 16 + l16) * 40 + quad * 8];
            acc[0][nt] = mfma32(a0, bfr, acc[0][nt]);
            acc[1][nt] = mfma32(a1, bfr, acc[1][nt]);
        }
    }

    _Float16* dst = wch ? gh : fh;
    const float* bias = wch ? bgv : bfv;
#pragma unroll
    for (int nt = 0; nt < 8; ++nt) {
        int col = nt * 16 + l16;
        float bv = bias[col];
#pragma unroll
        for (int ms = 0; ms < 2; ++ms)
#pragma unroll
            for (int rg = 0; rg < 4; ++rg) {
                int row = row0 + wr + ms * 16 + quad * 4 + rg;
                dst[(size_t)row * A_ + col] = (_Float16)(acc[ms][nt][rg] + bv);
            }
    }
}

// ---------------------------------------------------------------------------
// Kernel 2: MFMA flash attention, TM=64 keys/iter, all-K=32 MFMA.
// g rows are PERMUTED at the staging write (slot pi(j)) so the two QK S^T
// C-frags form the K=32 PV A-fragment (k=quad*8+reg) with zero shuffles.
// l-sum kept per-lane (l_part); cross-quad reduction once after the loop.
// LDS: gS 64x136 (17.4KB), xTs 256x72 (36.9KB) = 54.3KB -> 2 blocks/CU.
// ---------------------------------------------------------------------------
__global__ __launch_bounds__(256, 2) void attn_kernel(
    const float* __restrict__ x, const _Float16* __restrict__ f,
    const _Float16* __restrict__ g, const _Float16* __restrict__ xT,
    float* __restrict__ out)
{
    __shared__ __align__(16) _Float16 gS[64 * 136];
    __shared__ __align__(16) _Float16 xTs[256 * 72];

    const int dch = blockIdx.x;        // 0..3
    const int nt  = blockIdx.y;        // 0..15
    const int b   = blockIdx.z;
    const int tid = threadIdx.x;
    const int wave = tid >> 6, lane = tid & 63;
    const int quad = lane >> 4, l16 = lane & 15;
    const int d0 = dch * 256;
    const int qbase = nt * 128 + wave * 32;

    // f B-frags in regs: B[k=att][n=query]: n=l16, k=quad*8+j
    half8v fb[2][4];
#pragma unroll
    for (int it = 0; it < 2; ++it)
#pragma unroll
        for (int kc = 0; kc < 4; ++kc)
            fb[it][kc] = *(const half8v*)(f +
                ((size_t)(b * N_ + qbase + it * 16 + l16)) * A_ + kc * 32 + quad * 8);

    uint4 gR[4];
    uint4 xR[8];
#define AT_LOAD_TILE(M0)                                                      \
    {                                                                         \
        _Pragma("unroll")                                                     \
        for (int s = 0; s < 4; ++s) {                                         \
            int idx = tid + 256 * s;                                          \
            int r = idx >> 4, c = idx & 15;                                   \
            gR[s] = *(const uint4*)(g + ((size_t)(b * N_ + (M0) + r)) * A_ + c * 8); \
        }                                                                     \
        _Pragma("unroll")                                                     \
        for (int s = 0; s < 8; ++s) {                                         \
            int idx = tid + 256 * s;                                          \
            int rr = idx >> 3, jc = idx & 7;                                  \
            xR[s] = *(const uint4*)(xT + ((size_t)b * D_ + d0 + rr) * N_ + (M0) + jc * 8); \
        }                                                                     \
    }

    AT_LOAD_TILE(0)

    floatx4 acc[2][16];
#pragma unroll
    for (int it = 0; it < 2; ++it)
#pragma unroll
        for (int dt = 0; dt < 16; ++dt)
            acc[it][dt] = (floatx4){0.f, 0.f, 0.f, 0.f};
    float m_i[2]    = {-3.0e38f, -3.0e38f};
    float l_part[2] = {0.f, 0.f};

    for (int m0 = 0; m0 < N_; m0 += 64) {
        __syncthreads();
        // commit g with slot permutation: slot = (r&32) + ((r>>2)&1)*16
        //                                      + ((r>>3)&3)*4 + (r&3)
#pragma unroll
        for (int s = 0; s < 4; ++s) {
            int idx = tid + 256 * s;
            int r = idx >> 4, c = idx & 15;
            int slot = (r & 32) + ((r >> 2) & 1) * 16 + ((r >> 3) & 3) * 4 + (r & 3);
            *(uint4*)&gS[slot * 136 + c * 8] = gR[s];
        }
#pragma unroll
        for (int s = 0; s < 8; ++s) {
            int idx = tid + 256 * s;
            int rr = idx >> 3, jc = idx & 7;
            *(uint4*)&xTs[rr * 72 + jc * 8] = xR[s];
        }
        __syncthreads();
        if (m0 + 64 < N_) AT_LOAD_TILE(m0 + 64)

        // ---- QK: S^T, A=g slots (fragA rows l16, fragB rows 16+l16) ----
        floatx4 sc[2][2][2];     // [kb][frag][it]
#pragma unroll
        for (int kb = 0; kb < 2; ++kb)
#pragma unroll
            for (int fr = 0; fr < 2; ++fr)
#pragma unroll
                for (int it = 0; it < 2; ++it)
                    sc[kb][fr][it] = (floatx4){0.f, 0.f, 0.f, 0.f};
#pragma unroll
        for (int kc = 0; kc < 4; ++kc)
#pragma unroll
            for (int kb = 0; kb < 2; ++kb) {
                half8v ga0 = *(const half8v*)&gS[(kb * 32 + l16) * 136 + kc * 32 + quad * 8];
                half8v ga1 = *(const half8v*)&gS[(kb * 32 + 16 + l16) * 136 + kc * 32 + quad * 8];
                sc[kb][0][0] = mfma32(ga0, fb[0][kc], sc[kb][0][0]);
                sc[kb][0][1] = mfma32(ga0, fb[1][kc], sc[kb][0][1]);
                sc[kb][1][0] = mfma32(ga1, fb[0][kc], sc[kb][1][0]);
                sc[kb][1][1] = mfma32(ga1, fb[1][kc], sc[kb][1][1]);
            }

        // ---- lazy online softmax (per query i=l16, per i-tile) ----
        float tm[2];
#pragma unroll
        for (int it = 0; it < 2; ++it) {
            float tv = -3.0e38f;
#pragma unroll
            for (int kb = 0; kb < 2; ++kb)
#pragma unroll
                for (int fr = 0; fr < 2; ++fr)
#pragma unroll
                    for (int r = 0; r < 4; ++r)
                        tv = fmaxf(tv, sc[kb][fr][it][r]);
            tv = fmaxf(tv, __shfl_xor(tv, 16));
            tv = fmaxf(tv, __shfl_xor(tv, 32));
            tm[it] = tv;
        }
        bool needl = (tm[0] > m_i[0] + 8.0f) || (tm[1] > m_i[1] + 8.0f);
        if (__any(needl)) {
            float alpha[2];
#pragma unroll
            for (int it = 0; it < 2; ++it) {
                float mnew = fmaxf(m_i[it], tm[it]);
                alpha[it] = __expf(m_i[it] - mnew);   // first tile: exp(-inf)=0
                m_i[it] = mnew;
                l_part[it] *= alpha[it];
            }
            float ar[2][4];
#pragma unroll
            for (int it = 0; it < 2; ++it)
#pragma unroll
                for (int r = 0; r < 4; ++r)
                    ar[it][r] = __shfl(alpha[it], quad * 4 + r);
#pragma unroll
            for (int it = 0; it < 2; ++it)
#pragma unroll
                for (int dt = 0; dt < 16; ++dt)
#pragma unroll
                    for (int r = 0; r < 4; ++r)
                        acc[it][dt][r] *= ar[it][r];
        }

        // exp + pack: pa[kb][it] = K=32 A-frag (keys quad*8+0..7 + kb*32)
        half8v pa[2][2];
#pragma unroll
        for (int it = 0; it < 2; ++it) {
            float rs = 0.f;
#pragma unroll
            for (int kb = 0; kb < 2; ++kb) {
                float e0 = __expf(sc[kb][0][it][0] - m_i[it]);
                float e1 = __expf(sc[kb][0][it][1] - m_i[it]);
                float e2 = __expf(sc[kb][0][it][2] - m_i[it]);
                float e3 = __expf(sc[kb][0][it][3] - m_i[it]);
                float e4 = __expf(sc[kb][1][it][0] - m_i[it]);
                float e5 = __expf(sc[kb][1][it][1] - m_i[it]);
                float e6 = __expf(sc[kb][1][it][2] - m_i[it]);
                float e7 = __expf(sc[kb][1][it][3] - m_i[it]);
                rs += ((e0 + e1) + (e2 + e3)) + ((e4 + e5) + (e6 + e7));
                pa[kb][it] = (half8v){(_Float16)e0, (_Float16)e1, (_Float16)e2,
                                      (_Float16)e3, (_Float16)e4, (_Float16)e5,
                                      (_Float16)e6, (_Float16)e7};
            }
            l_part[it] += rs;
        }

        // ---- PV: K=32 MFMA, B = xTs[d][j] (b128, j-contiguous) ----
#pragma unroll
        for (int dt = 0; dt < 16; ++dt) {
            const int ro = (dt * 16 + l16) * 72;
            half8v xb0 = *(const half8v*)&xTs[ro + quad * 8];
            half8v xb1 = *(const half8v*)&xTs[ro + 32 + quad * 8];
            acc[0][dt] = mfma32(pa[0][0], xb0, acc[0][dt]);
            acc[0][dt] = mfma32(pa[1][0], xb1, acc[0][dt]);
            acc[1][dt] = mfma32(pa[0][1], xb0, acc[1][dt]);
            acc[1][dt] = mfma32(pa[1][1], xb1, acc[1][dt]);
        }
    }

    // ---- final l reduction (hoisted out of the loop) + epilogue ----
    float l_i[2];
#pragma unroll
    for (int it = 0; it < 2; ++it) {
        float rs = l_part[it];
        rs += __shfl_xor(rs, 16);
        rs += __shfl_xor(rs, 32);
        l_i[it] = rs;
    }
    float linv[2][4];
#pragma unroll
    for (int it = 0; it < 2; ++it)
#pragma unroll
        for (int r = 0; r < 4; ++r)
            linv[it][r] = 1.0f / __shfl(l_i[it], quad * 4 + r);

#pragma unroll
    for (int it = 0; it < 2; ++it)
#pragma unroll
        for (int r = 0; r < 4; ++r) {
            const size_t rowoff =
                ((size_t)(b * N_ + qbase + it * 16 + quad * 4 + r)) * D_ + d0;
#pragma unroll
            for (int dt = 0; dt < 16; ++dt) {
                int col = dt * 16 + l16;
                out[rowoff + col] = fmaf(acc[it][dt][r], linv[it][r], x[rowoff + col]);
            }
        }
}

extern "C" void kernel_launch(void* const* d_in, const int* in_sizes, int n_in,
                              void* d_out, int out_size, void* d_ws, size_t ws_size,
                              hipStream_t stream) {
    const float* x   = (const float*)d_in[0];
    const float* Wf  = (const float*)d_in[1];
    const float* bfv = (const float*)d_in[2];
    const float* Wg  = (const float*)d_in[3];
    const float* bgv = (const float*)d_in[4];
    float* out = (float*)d_out;

    // ws (f16 elements): fh[2.1M] gh[2.1M] xT[16.8M] whT[0.26M]  = 42.5 MB
    _Float16* fh  = (_Float16*)d_ws;
    _Float16* gh  = fh + (size_t)B_ * N_ * A_;
    _Float16* xT  = gh + (size_t)B_ * N_ * A_;
    _Float16* whT = xT + (size_t)B_ * D_ * N_;

    hipLaunchKernelGGL(xpose_kernel, dim3(N_ / 64, D_ / 64, B_), dim3(256), 0, stream,
                       x, xT);
    hipLaunchKernelGGL(wprep_kernel, dim3(D_ / 64, A_ / 64, 2), dim3(256), 0, stream,
                       Wf, Wg, whT);
    hipLaunchKernelGGL(fgmm_kernel, dim3(B_ * N_ / 64), dim3(256), 0, stream,
                       x, whT, bfv, bgv, fh, gh);
    hipLaunchKernelGGL(attn_kernel, dim3(D_ / 256, N_ / 128, B_), dim3(256), 0, stream,
                       x, fh, gh, xT, out);
}

// Round 7
// 323.522 us; speedup vs baseline: 1.6663x; 1.6663x over previous
//
#include <hip/hip_runtime.h>
#include <hip/hip_fp16.h>

// Problem: B=8, N=2048, D=1024, ATT=128   (all I/O float32)
//   f = x@Wf + bf ; g = x@Wg + bg ; out = softmax(f g^T) @ x + x
// Round 7: revert attn to TM=32 (round-5 register budget; round-6's TM=64
// spilled ~1GB to scratch) but KEEP the K=32 PV: g rows permuted at the
// staging write so the two QK S^T C-frags concatenate into the K=32 PV
// A-frag (k=quad*8+reg). PV: 32 full-rate MFMA/iter (was 64 half-rate).
// l-sum reduction hoisted out of the loop.

#define B_ 8
#define N_ 2048
#define D_ 1024
#define A_ 128

typedef _Float16 half8v  __attribute__((ext_vector_type(8)));
typedef _Float16 half4v  __attribute__((ext_vector_type(4)));
typedef float    floatx4 __attribute__((ext_vector_type(4)));

__device__ __forceinline__ floatx4 mfma32(half8v a, half8v b, floatx4 c) {
#if defined(__HIP_DEVICE_COMPILE__)
    return __builtin_amdgcn_mfma_f32_16x16x32_f16(a, b, c, 0, 0, 0);
#else
    return c;
#endif
}

// ---------------------------------------------------------------------------
// Kernel 0: transpose+convert x [b][n][d] fp32 -> xT [b][d][n] f16.
// ---------------------------------------------------------------------------
__global__ __launch_bounds__(256) void xpose_kernel(
    const float* __restrict__ x, _Float16* __restrict__ xT)
{
    __shared__ __align__(16) _Float16 ts[64][80];
    const int n0 = blockIdx.x * 64, d0 = blockIdx.y * 64, b = blockIdx.z;
    const int t = threadIdx.x;
#pragma unroll
    for (int s = 0; s < 4; ++s) {
        int idx = t + 256 * s;
        int nl = idx >> 4, c4 = idx & 15;
        float4 v = ((const float4*)(x + ((size_t)(b * N_ + n0 + nl)) * D_ + d0))[c4];
        ts[c4 * 4 + 0][nl] = (_Float16)v.x;
        ts[c4 * 4 + 1][nl] = (_Float16)v.y;
        ts[c4 * 4 + 2][nl] = (_Float16)v.z;
        ts[c4 * 4 + 3][nl] = (_Float16)v.w;
    }
    __syncthreads();
#pragma unroll
    for (int s = 0; s < 2; ++s) {
        int idx = t + 256 * s;
        int dl = idx >> 3, c = idx & 7;
        *(uint4*)&xT[((size_t)b * D_ + d0 + dl) * N_ + n0 + c * 8] =
            *(const uint4*)&ts[dl][c * 8];
    }
}

// ---------------------------------------------------------------------------
// Kernel 0b: W [1024][128] f32 -> whT [2][128][1024] f16 (transposed, K-major)
// ---------------------------------------------------------------------------
__global__ __launch_bounds__(256) void wprep_kernel(
    const float* __restrict__ Wf, const float* __restrict__ Wg,
    _Float16* __restrict__ whT)
{
    __shared__ __align__(16) _Float16 ts[64][72];
    const int k0 = blockIdx.x * 64, c0 = blockIdx.y * 64;
    const float* W = blockIdx.z ? Wg : Wf;
    _Float16* dst = whT + (size_t)blockIdx.z * A_ * D_;
    const int t = threadIdx.x;
#pragma unroll
    for (int s = 0; s < 4; ++s) {
        int idx = t + 256 * s;
        int kl = idx >> 4, c4 = idx & 15;
        float4 v = *(const float4*)&W[(size_t)(k0 + kl) * A_ + c0 + c4 * 4];
        ts[c4 * 4 + 0][kl] = (_Float16)v.x;
        ts[c4 * 4 + 1][kl] = (_Float16)v.y;
        ts[c4 * 4 + 2][kl] = (_Float16)v.z;
        ts[c4 * 4 + 3][kl] = (_Float16)v.w;
    }
    __syncthreads();
#pragma unroll
    for (int s = 0; s < 2; ++s) {
        int idx = t + 256 * s;
        int cl = idx >> 3, ch = idx & 7;
        *(uint4*)&dst[(size_t)(c0 + cl) * D_ + k0 + ch * 8] =
            *(const uint4*)&ts[cl][ch * 8];
    }
}

// ---------------------------------------------------------------------------
// Kernel 1: MFMA GEMM, f AND g per block (x staged once).
// Block 64 rows x 256 cols (f:0-127, g:128-255), 4 waves 2x2 (32 rows x 128
// cols each). K-tile 32 with register prefetch; LDS stride 40 halves.
// ---------------------------------------------------------------------------
__global__ __launch_bounds__(256) void fgmm_kernel(
    const float* __restrict__ x, const _Float16* __restrict__ whT,
    const float* __restrict__ bfv, const float* __restrict__ bgv,
    _Float16* __restrict__ fh, _Float16* __restrict__ gh)
{
    __shared__ __align__(16) _Float16 xs[64 * 40];
    __shared__ __align__(16) _Float16 wt[256 * 40];
    const int row0 = blockIdx.x * 64;
    const int t = threadIdx.x;
    const int w = t >> 6, lane = t & 63, quad = lane >> 4, l16 = lane & 15;
    const int wr  = (w >> 1) * 32;          // wave row base
    const int wch = (w & 1);                // 0 = f cols, 1 = g cols

    float4 xRf[2];
    uint4  wR[4];
#define FG_LOAD_TILE(K0)                                                      \
    {                                                                         \
        _Pragma("unroll")                                                     \
        for (int s = 0; s < 2; ++s) {                                         \
            int idx = t + 256 * s;                                            \
            int r = idx >> 3, k4 = idx & 7;                                   \
            xRf[s] = *(const float4*)&x[(size_t)(row0 + r) * D_ + (K0) + k4 * 4]; \
        }                                                                     \
        _Pragma("unroll")                                                     \
        for (int s = 0; s < 4; ++s) {                                         \
            int idx = t + 256 * s;                                            \
            int c = idx >> 2, k8 = idx & 3;                                   \
            wR[s] = *(const uint4*)&whT[(size_t)c * D_ + (K0) + k8 * 8];      \
        }                                                                     \
    }

    FG_LOAD_TILE(0)

    floatx4 acc[2][8];
#pragma unroll
    for (int ms = 0; ms < 2; ++ms)
#pragma unroll
        for (int nt = 0; nt < 8; ++nt)
            acc[ms][nt] = (floatx4){0.f, 0.f, 0.f, 0.f};

    for (int kt = 0; kt < 32; ++kt) {
        __syncthreads();
#pragma unroll
        for (int s = 0; s < 2; ++s) {
            int idx = t + 256 * s;
            int r = idx >> 3, k4 = idx & 7;
            half4v h = {(_Float16)xRf[s].x, (_Float16)xRf[s].y,
                        (_Float16)xRf[s].z, (_Float16)xRf[s].w};
            *(half4v*)&xs[r * 40 + k4 * 4] = h;
        }
#pragma unroll
        for (int s = 0; s < 4; ++s) {
            int idx = t + 256 * s;
            int c = idx >> 2, k8 = idx & 3;
            *(uint4*)&wt[c * 40 + k8 * 8] = wR[s];
        }
        __syncthreads();
        if (kt < 31) FG_LOAD_TILE((kt + 1) * 32)

        half8v a0 = *(const half8v*)&xs[(wr + l16) * 40 + quad * 8];
        half8v a1 = *(const half8v*)&xs[(wr + 16 + l16) * 40 + quad * 8];
#pragma unroll
        for (int nt = 0; nt < 8; ++nt) {
            half8v bfr = *(const half8v*)&wt[(wch * 128 + nt * 16 + l16) * 40 + quad * 8];
            acc[0][nt] = mfma32(a0, bfr, acc[0][nt]);
            acc[1][nt] = mfma32(a1, bfr, acc[1][nt]);
        }
    }

    _Float16* dst = wch ? gh : fh;
    const float* bias = wch ? bgv : bfv;
#pragma unroll
    for (int nt = 0; nt < 8; ++nt) {
        int col = nt * 16 + l16;
        float bv = bias[col];
#pragma unroll
        for (int ms = 0; ms < 2; ++ms)
#pragma unroll
            for (int rg = 0; rg < 4; ++rg) {
                int row = row0 + wr + ms * 16 + quad * 4 + rg;
                dst[(size_t)row * A_ + col] = (_Float16)(acc[ms][nt][rg] + bv);
            }
    }
}

// ---------------------------------------------------------------------------
// Kernel 2: MFMA flash attention. TM=32 (round-5 register budget), K=32 PV.
// g rows permuted at staging: slot(j) = ((j>>2)&1)*16 + ((j>>3)&3)*4 + (j&3)
//   => sc[0] regs hold keys quad*8+0..3, sc[1] regs keys quad*8+4..7, i.e.
//   concat(exp(sc[0]),exp(sc[1])) IS the K=32 A-frag. xTs plain layout
//   (stride 40): B-frag = b128 read of keys quad*8..+7 per d-row.
// LDS: gS 32x136 (8.7KB) + xTs 256x40 (20.5KB) = 29.2KB -> 2 blocks/CU.
// ---------------------------------------------------------------------------
__global__ __launch_bounds__(256, 2) void attn_kernel(
    const float* __restrict__ x, const _Float16* __restrict__ f,
    const _Float16* __restrict__ g, const _Float16* __restrict__ xT,
    float* __restrict__ out)
{
    __shared__ __align__(16) _Float16 gS[32 * 136];
    __shared__ __align__(16) _Float16 xTs[256 * 40];

    const int dch = blockIdx.x;
    const int nt  = blockIdx.y;
    const int b   = blockIdx.z;
    const int tid = threadIdx.x;
    const int wave = tid >> 6, lane = tid & 63;
    const int quad = lane >> 4, l16 = lane & 15;
    const int d0 = dch * 256;
    const int qbase = nt * 128 + wave * 32;

    // f B-frags in regs: B[k=att][n=query]: n=l16, k=quad*8+j
    half8v fb[2][4];
#pragma unroll
    for (int it = 0; it < 2; ++it)
#pragma unroll
        for (int kc = 0; kc < 4; ++kc)
            fb[it][kc] = *(const half8v*)(f +
                ((size_t)(b * N_ + qbase + it * 16 + l16)) * A_ + kc * 32 + quad * 8);

    uint4 gR[2];
    uint2 xR[8];
#define AT_LOAD_TILE(M0)                                                      \
    {                                                                         \
        _Pragma("unroll")                                                     \
        for (int s = 0; s < 2; ++s) {                                         \
            int idx = tid + 256 * s;                                          \
            int r = idx >> 4, c = idx & 15;                                   \
            gR[s] = *(const uint4*)(g + ((size_t)(b * N_ + (M0) + r)) * A_ + c * 8); \
        }                                                                     \
        _Pragma("unroll")                                                     \
        for (int s = 0; s < 8; ++s) {                                         \
            int idx = tid + 256 * s;                                          \
            int rr = idx >> 3, p = idx & 7;                                   \
            xR[s] = *(const uint2*)(xT + ((size_t)b * D_ + d0 + rr) * N_ + (M0) + p * 4); \
        }                                                                     \
    }

    AT_LOAD_TILE(0)

    floatx4 acc[2][16];
#pragma unroll
    for (int it = 0; it < 2; ++it)
#pragma unroll
        for (int dt = 0; dt < 16; ++dt)
            acc[it][dt] = (floatx4){0.f, 0.f, 0.f, 0.f};
    float m_i[2]    = {-3.0e38f, -3.0e38f};
    float l_part[2] = {0.f, 0.f};

    for (int m0 = 0; m0 < N_; m0 += 32) {
        __syncthreads();
        // commit g tile with slot permutation (keys j -> slot pi(j))
#pragma unroll
        for (int s = 0; s < 2; ++s) {
            int idx = tid + 256 * s;
            int r = idx >> 4, c = idx & 15;
            int slot = ((r >> 2) & 1) * 16 + ((r >> 3) & 3) * 4 + (r & 3);
            *(uint4*)&gS[slot * 136 + c * 8] = gR[s];
        }
        // commit xT tile (plain contiguous keys)
#pragma unroll
        for (int s = 0; s < 8; ++s) {
            int idx = tid + 256 * s;
            int rr = idx >> 3, p = idx & 7;
            *(uint2*)&xTs[rr * 40 + p * 4] = xR[s];
        }
        __syncthreads();
        if (m0 + 32 < N_) AT_LOAD_TILE(m0 + 32)

        // ---- QK: S^T, A = g slots (frag0 rows l16, frag1 rows 16+l16) ----
        floatx4 sc[2][2];    // [fr][it]
#pragma unroll
        for (int fr = 0; fr < 2; ++fr)
#pragma unroll
            for (int it = 0; it < 2; ++it)
                sc[fr][it] = (floatx4){0.f, 0.f, 0.f, 0.f};
#pragma unroll
        for (int kc = 0; kc < 4; ++kc) {
            half8v ga0 = *(const half8v*)&gS[(l16     ) * 136 + kc * 32 + quad * 8];
            half8v ga1 = *(const half8v*)&gS[(l16 + 16) * 136 + kc * 32 + quad * 8];
            sc[0][0] = mfma32(ga0, fb[0][kc], sc[0][0]);
            sc[0][1] = mfma32(ga0, fb[1][kc], sc[0][1]);
            sc[1][0] = mfma32(ga1, fb[0][kc], sc[1][0]);
            sc[1][1] = mfma32(ga1, fb[1][kc], sc[1][1]);
        }

        // ---- lazy online softmax (per query i=l16, per i-tile) ----
        float tm[2];
#pragma unroll
        for (int it = 0; it < 2; ++it) {
            float t0 = fmaxf(fmaxf(sc[0][it][0], sc[0][it][1]),
                             fmaxf(sc[0][it][2], sc[0][it][3]));
            float t1 = fmaxf(fmaxf(sc[1][it][0], sc[1][it][1]),
                             fmaxf(sc[1][it][2], sc[1][it][3]));
            float tv = fmaxf(t0, t1);
            tv = fmaxf(tv, __shfl_xor(tv, 16));
            tv = fmaxf(tv, __shfl_xor(tv, 32));
            tm[it] = tv;
        }
        bool needl = (tm[0] > m_i[0] + 8.0f) || (tm[1] > m_i[1] + 8.0f);
        if (__any(needl)) {
            float alpha[2];
#pragma unroll
            for (int it = 0; it < 2; ++it) {
                float mnew = fmaxf(m_i[it], tm[it]);
                alpha[it] = __expf(m_i[it] - mnew);   // first tile: exp(-inf)=0
                m_i[it] = mnew;
                l_part[it] *= alpha[it];
            }
            float ar[2][4];
#pragma unroll
            for (int it = 0; it < 2; ++it)
#pragma unroll
                for (int r = 0; r < 4; ++r)
                    ar[it][r] = __shfl(alpha[it], quad * 4 + r);
#pragma unroll
            for (int it = 0; it < 2; ++it)
#pragma unroll
                for (int dt = 0; dt < 16; ++dt)
#pragma unroll
                    for (int r = 0; r < 4; ++r)
                        acc[it][dt][r] *= ar[it][r];
        }

        // exp + pack: pa[it] = K=32 A-frag (keys quad*8 + 0..7)
        half8v pa[2];
#pragma unroll
        for (int it = 0; it < 2; ++it) {
            float e0 = __expf(sc[0][it][0] - m_i[it]);
            float e1 = __expf(sc[0][it][1] - m_i[it]);
            float e2 = __expf(sc[0][it][2] - m_i[it]);
            float e3 = __expf(sc[0][it][3] - m_i[it]);
            float e4 = __expf(sc[1][it][0] - m_i[it]);
            float e5 = __expf(sc[1][it][1] - m_i[it]);
            float e6 = __expf(sc[1][it][2] - m_i[it]);
            float e7 = __expf(sc[1][it][3] - m_i[it]);
            l_part[it] += ((e0 + e1) + (e2 + e3)) + ((e4 + e5) + (e6 + e7));
            pa[it] = (half8v){(_Float16)e0, (_Float16)e1, (_Float16)e2,
                              (_Float16)e3, (_Float16)e4, (_Float16)e5,
                              (_Float16)e6, (_Float16)e7};
        }

        // ---- PV: K=32 MFMA, B = xTs rows (b128, keys quad*8..+7) ----
#pragma unroll
        for (int dt = 0; dt < 16; ++dt) {
            half8v xb = *(const half8v*)&xTs[(dt * 16 + l16) * 40 + quad * 8];
            acc[0][dt] = mfma32(pa[0], xb, acc[0][dt]);
            acc[1][dt] = mfma32(pa[1], xb, acc[1][dt]);
        }
    }

    // ---- final l reduction (hoisted) + epilogue ----
    float l_i[2];
#pragma unroll
    for (int it = 0; it < 2; ++it) {
        float rs = l_part[it];
        rs += __shfl_xor(rs, 16);
        rs += __shfl_xor(rs, 32);
        l_i[it] = rs;
    }
    float linv[2][4];
#pragma unroll
    for (int it = 0; it < 2; ++it)
#pragma unroll
        for (int r = 0; r < 4; ++r)
            linv[it][r] = 1.0f / __shfl(l_i[it], quad * 4 + r);

#pragma unroll
    for (int it = 0; it < 2; ++it)
#pragma unroll
        for (int r = 0; r < 4; ++r) {
            const size_t rowoff =
                ((size_t)(b * N_ + qbase + it * 16 + quad * 4 + r)) * D_ + d0;
#pragma unroll
            for (int dt = 0; dt < 16; ++dt) {
                int col = dt * 16 + l16;
                out[rowoff + col] = fmaf(acc[it][dt][r], linv[it][r], x[rowoff + col]);
            }
        }
}

extern "C" void kernel_launch(void* const* d_in, const int* in_sizes, int n_in,
                              void* d_out, int out_size, void* d_ws, size_t ws_size,
                              hipStream_t stream) {
    const float* x   = (const float*)d_in[0];
    const float* Wf  = (const float*)d_in[1];
    const float* bfv = (const float*)d_in[2];
    const float* Wg  = (const float*)d_in[3];
    const float* bgv = (const float*)d_in[4];
    float* out = (float*)d_out;

    // ws (f16 elements): fh[2.1M] gh[2.1M] xT[16.8M] whT[0.26M]  = 42.5 MB
    _Float16* fh  = (_Float16*)d_ws;
    _Float16* gh  = fh + (size_t)B_ * N_ * A_;
    _Float16* xT  = gh + (size_t)B_ * N_ * A_;
    _Float16* whT = xT + (size_t)B_ * D_ * N_;

    hipLaunchKernelGGL(xpose_kernel, dim3(N_ / 64, D_ / 64, B_), dim3(256), 0, stream,
                       x, xT);
    hipLaunchKernelGGL(wprep_kernel, dim3(D_ / 64, A_ / 64, 2), dim3(256), 0, stream,
                       Wf, Wg, whT);
    hipLaunchKernelGGL(fgmm_kernel, dim3(B_ * N_ / 64), dim3(256), 0, stream,
                       x, whT, bfv, bgv, fh, gh);
    hipLaunchKernelGGL(attn_kernel, dim3(D_ / 256, N_ / 128, B_), dim3(256), 0, stream,
                       x, fh, gh, xT, out);
}